// Round 1
// baseline (44.245 us; speedup 1.0000x reference)
//
#include <hip/hip_runtime.h>
#include <math.h>

#define NBLK 2048
#define NTHR 256
#define B_ 4
#define F_ 512
#define N_ 1024
#define V_ 4

struct Partial {
  double sum_diff2;
  double sum_dist;
  double sum_acc2;
  double cnt;
  float gmin[3], gmax[3], pmin[3], pmax[3];
};

__global__ __launch_bounds__(NTHR) void loss_main(
    const float* __restrict__ pred, const float* __restrict__ gt,
    const int* __restrict__ vis, const float* __restrict__ P,
    const float* __restrict__ tracks, Partial* __restrict__ partials)
{
  __shared__ float sP[V_ * B_ * 12];
  for (int i = threadIdx.x; i < V_ * B_ * 12; i += NTHR) sP[i] = P[i];
  __syncthreads();

  double sum_diff2 = 0.0, sum_dist = 0.0, sum_acc2 = 0.0, cnt = 0.0;
  float gmin[3] = { INFINITY,  INFINITY,  INFINITY};
  float gmax[3] = {-INFINITY, -INFINITY, -INFINITY};
  float pmin[3] = { INFINITY,  INFINITY,  INFINITY};
  float pmax[3] = {-INFINITY, -INFINITY, -INFINITY};

  const int total = B_ * F_ * N_;
  for (int e = blockIdx.x * NTHR + threadIdx.x; e < total; e += NBLK * NTHR) {
    const int n = e & (N_ - 1);
    const int f = (e >> 10) & (F_ - 1);
    const int b = e >> 19;

    const float* pp = pred + (size_t)e * 3;
    const float p0 = pp[0], p1 = pp[1], p2 = pp[2];
    const float* gp = gt + (size_t)e * 3;
    const float g0 = gp[0], g1 = gp[1], g2 = gp[2];

    // ---- recon: masked diff^2, count, masked gt min/max
    if (vis[e]) {
      const float d0 = p0 - g0, d1 = p1 - g1, d2 = p2 - g2;
      sum_diff2 += (double)(d0 * d0) + (double)(d1 * d1) + (double)(d2 * d2);
      cnt += 1.0;
      gmin[0] = fminf(gmin[0], g0); gmax[0] = fmaxf(gmax[0], g0);
      gmin[1] = fminf(gmin[1], g1); gmax[1] = fmaxf(gmax[1], g1);
      gmin[2] = fminf(gmin[2], g2); gmax[2] = fmaxf(gmax[2], g2);
    }

    // ---- temporal scale: unmasked pred min/max
    pmin[0] = fminf(pmin[0], p0); pmax[0] = fmaxf(pmax[0], p0);
    pmin[1] = fminf(pmin[1], p1); pmax[1] = fmaxf(pmax[1], p1);
    pmin[2] = fminf(pmin[2], p2); pmax[2] = fmaxf(pmax[2], p2);

    // ---- identity: project into V views
#pragma unroll
    for (int v = 0; v < V_; ++v) {
      const float* Pm = sP + (v * B_ + b) * 12;
      const float a0 = Pm[0] * p0 + Pm[1] * p1 + Pm[2]  * p2 + Pm[3];
      const float a1 = Pm[4] * p0 + Pm[5] * p1 + Pm[6]  * p2 + Pm[7];
      const float a2 = Pm[8] * p0 + Pm[9] * p1 + Pm[10] * p2 + Pm[11];
      const float inv = 1.0f / (a2 + 1e-10f);
      const float x = a0 * inv, y = a1 * inv;
      const float* tp = tracks + ((((size_t)v * B_ + b) * F_ + f) * N_ + n) * 2;
      const float dx = x - tp[0], dy = y - tp[1];
      sum_dist += (double)dx * (double)dx + (double)dy * (double)dy;
    }

    // ---- temporal: second difference (valid for f < F-2)
    if (f < F_ - 2) {
      const float* q1 = pp + N_ * 3;
      const float* q2 = pp + 2 * N_ * 3;
      const float a0 = q2[0] - 2.0f * q1[0] + p0;
      const float a1 = q2[1] - 2.0f * q1[1] + p1;
      const float a2 = q2[2] - 2.0f * q1[2] + p2;
      sum_acc2 += (double)a0 * (double)a0 + (double)a1 * (double)a1 +
                  (double)a2 * (double)a2;
    }
  }

  // ---- block tree reduction (deterministic)
  __shared__ double sd[4][NTHR];
  __shared__ float  sf[12][NTHR];
  const int tid = threadIdx.x;
  sd[0][tid] = sum_diff2; sd[1][tid] = sum_dist;
  sd[2][tid] = sum_acc2;  sd[3][tid] = cnt;
#pragma unroll
  for (int k = 0; k < 3; ++k) {
    sf[k][tid]     = gmin[k];
    sf[3 + k][tid] = gmax[k];
    sf[6 + k][tid] = pmin[k];
    sf[9 + k][tid] = pmax[k];
  }
  __syncthreads();
  for (int s = NTHR / 2; s > 0; s >>= 1) {
    if (tid < s) {
#pragma unroll
      for (int k = 0; k < 4; ++k) sd[k][tid] += sd[k][tid + s];
#pragma unroll
      for (int k = 0; k < 3; ++k) {
        sf[k][tid]     = fminf(sf[k][tid],     sf[k][tid + s]);
        sf[3 + k][tid] = fmaxf(sf[3 + k][tid], sf[3 + k][tid + s]);
        sf[6 + k][tid] = fminf(sf[6 + k][tid], sf[6 + k][tid + s]);
        sf[9 + k][tid] = fmaxf(sf[9 + k][tid], sf[9 + k][tid + s]);
      }
    }
    __syncthreads();
  }
  if (tid == 0) {
    Partial p;
    p.sum_diff2 = sd[0][0]; p.sum_dist = sd[1][0];
    p.sum_acc2  = sd[2][0]; p.cnt      = sd[3][0];
#pragma unroll
    for (int k = 0; k < 3; ++k) {
      p.gmin[k] = sf[k][0];     p.gmax[k] = sf[3 + k][0];
      p.pmin[k] = sf[6 + k][0]; p.pmax[k] = sf[9 + k][0];
    }
    partials[blockIdx.x] = p;
  }
}

__global__ __launch_bounds__(NTHR) void loss_final(
    const Partial* __restrict__ partials, float* __restrict__ out)
{
  double sum_diff2 = 0.0, sum_dist = 0.0, sum_acc2 = 0.0, cnt = 0.0;
  float gmin[3] = { INFINITY,  INFINITY,  INFINITY};
  float gmax[3] = {-INFINITY, -INFINITY, -INFINITY};
  float pmin[3] = { INFINITY,  INFINITY,  INFINITY};
  float pmax[3] = {-INFINITY, -INFINITY, -INFINITY};

  const int tid = threadIdx.x;
  for (int i = tid; i < NBLK; i += NTHR) {   // fixed order -> deterministic
    const Partial p = partials[i];
    sum_diff2 += p.sum_diff2; sum_dist += p.sum_dist;
    sum_acc2  += p.sum_acc2;  cnt      += p.cnt;
#pragma unroll
    for (int k = 0; k < 3; ++k) {
      gmin[k] = fminf(gmin[k], p.gmin[k]); gmax[k] = fmaxf(gmax[k], p.gmax[k]);
      pmin[k] = fminf(pmin[k], p.pmin[k]); pmax[k] = fmaxf(pmax[k], p.pmax[k]);
    }
  }

  __shared__ double sd[4][NTHR];
  __shared__ float  sf[12][NTHR];
  sd[0][tid] = sum_diff2; sd[1][tid] = sum_dist;
  sd[2][tid] = sum_acc2;  sd[3][tid] = cnt;
#pragma unroll
  for (int k = 0; k < 3; ++k) {
    sf[k][tid]     = gmin[k];
    sf[3 + k][tid] = gmax[k];
    sf[6 + k][tid] = pmin[k];
    sf[9 + k][tid] = pmax[k];
  }
  __syncthreads();
  for (int s = NTHR / 2; s > 0; s >>= 1) {
    if (tid < s) {
#pragma unroll
      for (int k = 0; k < 4; ++k) sd[k][tid] += sd[k][tid + s];
#pragma unroll
      for (int k = 0; k < 3; ++k) {
        sf[k][tid]     = fminf(sf[k][tid],     sf[k][tid + s]);
        sf[3 + k][tid] = fmaxf(sf[3 + k][tid], sf[3 + k][tid + s]);
        sf[6 + k][tid] = fminf(sf[6 + k][tid], sf[6 + k][tid + s]);
        sf[9 + k][tid] = fmaxf(sf[9 + k][tid], sf[9 + k][tid + s]);
      }
    }
    __syncthreads();
  }

  if (tid == 0) {
    const double sdiff2 = sd[0][0], sdist = sd[1][0], sacc2 = sd[2][0];
    const double c = sd[3][0];

    // recon
    double sr = -INFINITY;
#pragma unroll
    for (int k = 0; k < 3; ++k) sr = fmax(sr, (double)sf[3 + k][0] - (double)sf[k][0]);
    sr += 1e-6;
    const double recon = sdiff2 / fmax(c * 3.0, 1.0) / (sr * sr);

    // identity: mean over V*B*F*N*2 of (p2d - t)^2 / 224
    const double ident = sdist / 224.0 / ((double)V_ * B_ * F_ * N_ * 2.0);

    // temporal
    double st = -INFINITY;
#pragma unroll
    for (int k = 0; k < 3; ++k) st = fmax(st, (double)sf[9 + k][0] - (double)sf[6 + k][0]);
    st += 1e-6;
    const double tloss = sacc2 / ((double)B_ * (F_ - 2) * N_);
    const double temp = tloss / (st * st);

    const double total = recon + ident + 0.5 * temp;
    out[0] = (float)total;
    out[1] = (float)recon;
    out[2] = (float)ident;
    out[3] = (float)temp;
  }
}

extern "C" void kernel_launch(void* const* d_in, const int* in_sizes, int n_in,
                              void* d_out, int out_size, void* d_ws, size_t ws_size,
                              hipStream_t stream) {
  const float* pred   = (const float*)d_in[0];
  const float* gt     = (const float*)d_in[1];
  const int*   vis    = (const int*)d_in[2];
  const float* P      = (const float*)d_in[3];
  const float* tracks = (const float*)d_in[4];
  float* out = (float*)d_out;
  Partial* partials = (Partial*)d_ws;

  loss_main<<<NBLK, NTHR, 0, stream>>>(pred, gt, vis, P, tracks, partials);
  loss_final<<<1, NTHR, 0, stream>>>(partials, out);
}

// Round 2
// 39.816 us; speedup vs baseline: 1.1112x; 1.1112x over previous
//
#include <hip/hip_runtime.h>
#include <math.h>

#define NBLK 2048
#define NTHR 256
#define B_ 4
#define F_ 512
#define N_ 1024
#define V_ 4

struct Partial {
  double sum_diff2;
  double sum_dist;
  double sum_acc2;
  double cnt;
  float gmin[3], gmax[3], pmin[3], pmax[3];
};

__global__ __launch_bounds__(NTHR) void loss_main(
    const float* __restrict__ pred, const float* __restrict__ gt,
    const int* __restrict__ vis, const float* __restrict__ P,
    const float* __restrict__ tracks, Partial* __restrict__ partials)
{
  __shared__ float sP[V_ * B_ * 12];
  if (threadIdx.x < V_ * B_ * 12) sP[threadIdx.x] = P[threadIdx.x];
  __syncthreads();

  const int q = blockIdx.x * NTHR + threadIdx.x;   // quad index, 0..524287
  const int e = q << 2;                            // first point of quad
  const int b = e >> 19;
  const int f = (e >> 10) & (F_ - 1);

  // ---- vectorized loads: pred & gt quads (12 floats each)
  const float4* pp4 = (const float4*)(pred + (size_t)e * 3);
  const float4 pA = pp4[0], pB = pp4[1], pC = pp4[2];
  const float px[4] = {pA.x, pA.w, pB.z, pC.y};
  const float py[4] = {pA.y, pB.x, pB.w, pC.z};
  const float pz[4] = {pA.z, pB.y, pC.x, pC.w};

  const float4* gp4 = (const float4*)(gt + (size_t)e * 3);
  const float4 gA = gp4[0], gB = gp4[1], gC = gp4[2];
  const float gx[4] = {gA.x, gA.w, gB.z, gC.y};
  const float gy[4] = {gA.y, gB.x, gB.w, gC.z};
  const float gz[4] = {gA.z, gB.y, gC.x, gC.w};

  const int4 vv = *(const int4*)(vis + e);
  const int vm[4] = {vv.x, vv.y, vv.z, vv.w};

  // ---- temporal neighbor quads (f+1, f+2), uniform branch per quad
  float sum_acc2 = 0.0f;
  if (f < F_ - 2) {
    const float4* q14 = (const float4*)(pred + (size_t)e * 3 + N_ * 3);
    const float4 aA = q14[0], aB = q14[1], aC = q14[2];
    const float ax[4] = {aA.x, aA.w, aB.z, aC.y};
    const float ay[4] = {aA.y, aB.x, aB.w, aC.z};
    const float az[4] = {aA.z, aB.y, aC.x, aC.w};
    const float4* q24 = (const float4*)(pred + (size_t)e * 3 + 2 * N_ * 3);
    const float4 cA = q24[0], cB = q24[1], cC = q24[2];
    const float cx[4] = {cA.x, cA.w, cB.z, cC.y};
    const float cy[4] = {cA.y, cB.x, cB.w, cC.z};
    const float cz[4] = {cA.z, cB.y, cC.x, cC.w};
#pragma unroll
    for (int i = 0; i < 4; ++i) {
      const float a0 = cx[i] - 2.0f * ax[i] + px[i];
      const float a1 = cy[i] - 2.0f * ay[i] + py[i];
      const float a2 = cz[i] - 2.0f * az[i] + pz[i];
      sum_acc2 += a0 * a0 + a1 * a1 + a2 * a2;
    }
  }

  // ---- recon + min/max
  float sum_diff2 = 0.0f;
  float cntf = 0.0f;
  float gmin[3] = { INFINITY,  INFINITY,  INFINITY};
  float gmax[3] = {-INFINITY, -INFINITY, -INFINITY};
  float pmin[3] = { INFINITY,  INFINITY,  INFINITY};
  float pmax[3] = {-INFINITY, -INFINITY, -INFINITY};
#pragma unroll
  for (int i = 0; i < 4; ++i) {
    pmin[0] = fminf(pmin[0], px[i]); pmax[0] = fmaxf(pmax[0], px[i]);
    pmin[1] = fminf(pmin[1], py[i]); pmax[1] = fmaxf(pmax[1], py[i]);
    pmin[2] = fminf(pmin[2], pz[i]); pmax[2] = fmaxf(pmax[2], pz[i]);
    if (vm[i]) {
      const float d0 = px[i] - gx[i], d1 = py[i] - gy[i], d2 = pz[i] - gz[i];
      sum_diff2 += d0 * d0 + d1 * d1 + d2 * d2;
      cntf += 1.0f;
      gmin[0] = fminf(gmin[0], gx[i]); gmax[0] = fmaxf(gmax[0], gx[i]);
      gmin[1] = fminf(gmin[1], gy[i]); gmax[1] = fmaxf(gmax[1], gy[i]);
      gmin[2] = fminf(gmin[2], gz[i]); gmax[2] = fmaxf(gmax[2], gz[i]);
    }
  }

  // ---- identity: project into V views, 2 float4 track loads per view
  float sum_dist = 0.0f;
  const size_t ewrap2 = (size_t)(e & (F_ * N_ - 1)) * 2;
#pragma unroll
  for (int v = 0; v < V_; ++v) {
    const float* Pm = sP + (v * B_ + b) * 12;
    const float4* tp4 =
        (const float4*)(tracks + ((size_t)(v * B_ + b) << 20) + ewrap2);
    const float4 t0 = tp4[0], t1 = tp4[1];
    const float tx[4] = {t0.x, t0.z, t1.x, t1.z};
    const float ty[4] = {t0.y, t0.w, t1.y, t1.w};
#pragma unroll
    for (int i = 0; i < 4; ++i) {
      const float a0 = Pm[0] * px[i] + Pm[1] * py[i] + Pm[2]  * pz[i] + Pm[3];
      const float a1 = Pm[4] * px[i] + Pm[5] * py[i] + Pm[6]  * pz[i] + Pm[7];
      const float a2 = Pm[8] * px[i] + Pm[9] * py[i] + Pm[10] * pz[i] + Pm[11];
      const float inv = 1.0f / (a2 + 1e-10f);
      const float dx = a0 * inv - tx[i];
      const float dy = a1 * inv - ty[i];
      sum_dist += dx * dx + dy * dy;
    }
  }

  // ---- wave shuffle reduction (deterministic tree)
  double d0 = (double)sum_diff2, d1 = (double)sum_dist;
  double d2 = (double)sum_acc2,  d3 = (double)cntf;
#pragma unroll
  for (int o = 32; o > 0; o >>= 1) {
    d0 += __shfl_down(d0, o);
    d1 += __shfl_down(d1, o);
    d2 += __shfl_down(d2, o);
    d3 += __shfl_down(d3, o);
#pragma unroll
    for (int k = 0; k < 3; ++k) {
      gmin[k] = fminf(gmin[k], __shfl_down(gmin[k], o));
      gmax[k] = fmaxf(gmax[k], __shfl_down(gmax[k], o));
      pmin[k] = fminf(pmin[k], __shfl_down(pmin[k], o));
      pmax[k] = fmaxf(pmax[k], __shfl_down(pmax[k], o));
    }
  }

  __shared__ Partial sw[NTHR / 64];
  const int lane = threadIdx.x & 63;
  const int wave = threadIdx.x >> 6;
  if (lane == 0) {
    Partial p;
    p.sum_diff2 = d0; p.sum_dist = d1; p.sum_acc2 = d2; p.cnt = d3;
#pragma unroll
    for (int k = 0; k < 3; ++k) {
      p.gmin[k] = gmin[k]; p.gmax[k] = gmax[k];
      p.pmin[k] = pmin[k]; p.pmax[k] = pmax[k];
    }
    sw[wave] = p;
  }
  __syncthreads();
  if (threadIdx.x == 0) {
    Partial p = sw[0];
#pragma unroll
    for (int w = 1; w < NTHR / 64; ++w) {
      p.sum_diff2 += sw[w].sum_diff2; p.sum_dist += sw[w].sum_dist;
      p.sum_acc2  += sw[w].sum_acc2;  p.cnt      += sw[w].cnt;
#pragma unroll
      for (int k = 0; k < 3; ++k) {
        p.gmin[k] = fminf(p.gmin[k], sw[w].gmin[k]);
        p.gmax[k] = fmaxf(p.gmax[k], sw[w].gmax[k]);
        p.pmin[k] = fminf(p.pmin[k], sw[w].pmin[k]);
        p.pmax[k] = fmaxf(p.pmax[k], sw[w].pmax[k]);
      }
    }
    partials[blockIdx.x] = p;
  }
}

__global__ __launch_bounds__(NTHR) void loss_final(
    const Partial* __restrict__ partials, float* __restrict__ out)
{
  double sum_diff2 = 0.0, sum_dist = 0.0, sum_acc2 = 0.0, cnt = 0.0;
  float gmin[3] = { INFINITY,  INFINITY,  INFINITY};
  float gmax[3] = {-INFINITY, -INFINITY, -INFINITY};
  float pmin[3] = { INFINITY,  INFINITY,  INFINITY};
  float pmax[3] = {-INFINITY, -INFINITY, -INFINITY};

  const int tid = threadIdx.x;
  for (int i = tid; i < NBLK; i += NTHR) {   // fixed order -> deterministic
    const Partial p = partials[i];
    sum_diff2 += p.sum_diff2; sum_dist += p.sum_dist;
    sum_acc2  += p.sum_acc2;  cnt      += p.cnt;
#pragma unroll
    for (int k = 0; k < 3; ++k) {
      gmin[k] = fminf(gmin[k], p.gmin[k]); gmax[k] = fmaxf(gmax[k], p.gmax[k]);
      pmin[k] = fminf(pmin[k], p.pmin[k]); pmax[k] = fmaxf(pmax[k], p.pmax[k]);
    }
  }

  // wave shuffle reduce then cross-wave LDS
#pragma unroll
  for (int o = 32; o > 0; o >>= 1) {
    sum_diff2 += __shfl_down(sum_diff2, o);
    sum_dist  += __shfl_down(sum_dist, o);
    sum_acc2  += __shfl_down(sum_acc2, o);
    cnt       += __shfl_down(cnt, o);
#pragma unroll
    for (int k = 0; k < 3; ++k) {
      gmin[k] = fminf(gmin[k], __shfl_down(gmin[k], o));
      gmax[k] = fmaxf(gmax[k], __shfl_down(gmax[k], o));
      pmin[k] = fminf(pmin[k], __shfl_down(pmin[k], o));
      pmax[k] = fmaxf(pmax[k], __shfl_down(pmax[k], o));
    }
  }

  __shared__ Partial sw[NTHR / 64];
  const int lane = tid & 63;
  const int wave = tid >> 6;
  if (lane == 0) {
    Partial p;
    p.sum_diff2 = sum_diff2; p.sum_dist = sum_dist;
    p.sum_acc2  = sum_acc2;  p.cnt      = cnt;
#pragma unroll
    for (int k = 0; k < 3; ++k) {
      p.gmin[k] = gmin[k]; p.gmax[k] = gmax[k];
      p.pmin[k] = pmin[k]; p.pmax[k] = pmax[k];
    }
    sw[wave] = p;
  }
  __syncthreads();

  if (tid == 0) {
    Partial p = sw[0];
#pragma unroll
    for (int w = 1; w < NTHR / 64; ++w) {
      p.sum_diff2 += sw[w].sum_diff2; p.sum_dist += sw[w].sum_dist;
      p.sum_acc2  += sw[w].sum_acc2;  p.cnt      += sw[w].cnt;
#pragma unroll
      for (int k = 0; k < 3; ++k) {
        p.gmin[k] = fminf(p.gmin[k], sw[w].gmin[k]);
        p.gmax[k] = fmaxf(p.gmax[k], sw[w].gmax[k]);
        p.pmin[k] = fminf(p.pmin[k], sw[w].pmin[k]);
        p.pmax[k] = fmaxf(p.pmax[k], sw[w].pmax[k]);
      }
    }

    // recon
    double sr = -INFINITY;
#pragma unroll
    for (int k = 0; k < 3; ++k) sr = fmax(sr, (double)p.gmax[k] - (double)p.gmin[k]);
    sr += 1e-6;
    const double recon = p.sum_diff2 / fmax(p.cnt * 3.0, 1.0) / (sr * sr);

    // identity
    const double ident = p.sum_dist / 224.0 / ((double)V_ * B_ * F_ * N_ * 2.0);

    // temporal
    double st = -INFINITY;
#pragma unroll
    for (int k = 0; k < 3; ++k) st = fmax(st, (double)p.pmax[k] - (double)p.pmin[k]);
    st += 1e-6;
    const double tloss = p.sum_acc2 / ((double)B_ * (F_ - 2) * N_);
    const double temp = tloss / (st * st);

    const double total = recon + ident + 0.5 * temp;
    out[0] = (float)total;
    out[1] = (float)recon;
    out[2] = (float)ident;
    out[3] = (float)temp;
  }
}

extern "C" void kernel_launch(void* const* d_in, const int* in_sizes, int n_in,
                              void* d_out, int out_size, void* d_ws, size_t ws_size,
                              hipStream_t stream) {
  const float* pred   = (const float*)d_in[0];
  const float* gt     = (const float*)d_in[1];
  const int*   vis    = (const int*)d_in[2];
  const float* P      = (const float*)d_in[3];
  const float* tracks = (const float*)d_in[4];
  float* out = (float*)d_out;
  Partial* partials = (Partial*)d_ws;

  loss_main<<<NBLK, NTHR, 0, stream>>>(pred, gt, vis, P, tracks, partials);
  loss_final<<<1, NTHR, 0, stream>>>(partials, out);
}

// Round 3
// 39.385 us; speedup vs baseline: 1.1234x; 1.0109x over previous
//
#include <hip/hip_runtime.h>
#include <math.h>

#define NBLK 2048
#define NTHR 256
#define B_ 4
#define F_ 512
#define N_ 1024
#define V_ 4

struct Partial {          // 64 B, all f32
  float sum_diff2;
  float sum_dist;
  float sum_acc2;
  float cnt;
  float gmin[3], gmax[3], pmin[3], pmax[3];
};

__global__ __launch_bounds__(NTHR, 4) void loss_main(
    const float* __restrict__ pred, const float* __restrict__ gt,
    const int* __restrict__ vis, const float* __restrict__ P,
    const float* __restrict__ tracks, Partial* __restrict__ partials)
{
  __shared__ float sP[V_ * B_ * 12];
  if (threadIdx.x < V_ * B_ * 12) sP[threadIdx.x] = P[threadIdx.x];
  __syncthreads();

  const int q = blockIdx.x * NTHR + threadIdx.x;   // quad index, 0..524287
  const int e = q << 2;                            // first point of quad
  const int b = e >> 19;
  const int f = (e >> 10) & (F_ - 1);
  const bool has_acc = (f < F_ - 2);

  // ================= ISSUE ALL LOADS FIRST (maximize MLP) =================
  const float4* pp4 = (const float4*)(pred + (size_t)e * 3);
  const float4 pA = pp4[0], pB = pp4[1], pC = pp4[2];

  const float4* gp4 = (const float4*)(gt + (size_t)e * 3);
  const float4 gA = gp4[0], gB = gp4[1], gC = gp4[2];

  const int4 vv = *(const int4*)(vis + e);

  // temporal neighbors: clamp address so we can load unconditionally
  const size_t nbase = (size_t)e * 3 + (has_acc ? (size_t)(N_ * 3) : 0);
  const size_t nbase2 = (size_t)e * 3 + (has_acc ? (size_t)(2 * N_ * 3) : 0);
  const float4* q14 = (const float4*)(pred + nbase);
  const float4 aA = q14[0], aB = q14[1], aC = q14[2];
  const float4* q24 = (const float4*)(pred + nbase2);
  const float4 cA = q24[0], cB = q24[1], cC = q24[2];

  const size_t ewrap2 = (size_t)(e & (F_ * N_ - 1)) * 2;
  const float4* tp0 = (const float4*)(tracks + ((size_t)(0 * B_ + b) << 20) + ewrap2);
  const float4* tp1 = (const float4*)(tracks + ((size_t)(1 * B_ + b) << 20) + ewrap2);
  const float4* tp2 = (const float4*)(tracks + ((size_t)(2 * B_ + b) << 20) + ewrap2);
  const float4* tp3 = (const float4*)(tracks + ((size_t)(3 * B_ + b) << 20) + ewrap2);
  const float4 t0a = tp0[0], t0b = tp0[1];
  const float4 t1a = tp1[0], t1b = tp1[1];
  const float4 t2a = tp2[0], t2b = tp2[1];
  const float4 t3a = tp3[0], t3b = tp3[1];

  // ========================= COMPUTE =========================
  const float px[4] = {pA.x, pA.w, pB.z, pC.y};
  const float py[4] = {pA.y, pB.x, pB.w, pC.z};
  const float pz[4] = {pA.z, pB.y, pC.x, pC.w};
  const float gx[4] = {gA.x, gA.w, gB.z, gC.y};
  const float gy[4] = {gA.y, gB.x, gB.w, gC.z};
  const float gz[4] = {gA.z, gB.y, gC.x, gC.w};
  const int vm[4] = {vv.x, vv.y, vv.z, vv.w};

  // temporal second difference
  float sum_acc2 = 0.0f;
  {
    const float ax[4] = {aA.x, aA.w, aB.z, aC.y};
    const float ay[4] = {aA.y, aB.x, aB.w, aC.z};
    const float az[4] = {aA.z, aB.y, aC.x, aC.w};
    const float cx[4] = {cA.x, cA.w, cB.z, cC.y};
    const float cy[4] = {cA.y, cB.x, cB.w, cC.z};
    const float cz[4] = {cA.z, cB.y, cC.x, cC.w};
#pragma unroll
    for (int i = 0; i < 4; ++i) {
      const float a0 = cx[i] - 2.0f * ax[i] + px[i];
      const float a1 = cy[i] - 2.0f * ay[i] + py[i];
      const float a2 = cz[i] - 2.0f * az[i] + pz[i];
      sum_acc2 += a0 * a0 + a1 * a1 + a2 * a2;
    }
    if (!has_acc) sum_acc2 = 0.0f;
  }

  // recon + min/max
  float sum_diff2 = 0.0f, cntf = 0.0f;
  float gmin[3] = { INFINITY,  INFINITY,  INFINITY};
  float gmax[3] = {-INFINITY, -INFINITY, -INFINITY};
  float pmin[3] = { INFINITY,  INFINITY,  INFINITY};
  float pmax[3] = {-INFINITY, -INFINITY, -INFINITY};
#pragma unroll
  for (int i = 0; i < 4; ++i) {
    pmin[0] = fminf(pmin[0], px[i]); pmax[0] = fmaxf(pmax[0], px[i]);
    pmin[1] = fminf(pmin[1], py[i]); pmax[1] = fmaxf(pmax[1], py[i]);
    pmin[2] = fminf(pmin[2], pz[i]); pmax[2] = fmaxf(pmax[2], pz[i]);
    if (vm[i]) {
      const float d0 = px[i] - gx[i], d1 = py[i] - gy[i], d2 = pz[i] - gz[i];
      sum_diff2 += d0 * d0 + d1 * d1 + d2 * d2;
      cntf += 1.0f;
      gmin[0] = fminf(gmin[0], gx[i]); gmax[0] = fmaxf(gmax[0], gx[i]);
      gmin[1] = fminf(gmin[1], gy[i]); gmax[1] = fmaxf(gmax[1], gy[i]);
      gmin[2] = fminf(gmin[2], gz[i]); gmax[2] = fmaxf(gmax[2], gz[i]);
    }
  }

  // identity projection, V=4 views
  float sum_dist = 0.0f;
  const float tx[V_][4] = {{t0a.x, t0a.z, t0b.x, t0b.z},
                           {t1a.x, t1a.z, t1b.x, t1b.z},
                           {t2a.x, t2a.z, t2b.x, t2b.z},
                           {t3a.x, t3a.z, t3b.x, t3b.z}};
  const float ty[V_][4] = {{t0a.y, t0a.w, t0b.y, t0b.w},
                           {t1a.y, t1a.w, t1b.y, t1b.w},
                           {t2a.y, t2a.w, t2b.y, t2b.w},
                           {t3a.y, t3a.w, t3b.y, t3b.w}};
#pragma unroll
  for (int v = 0; v < V_; ++v) {
    const float* Pm = sP + (v * B_ + b) * 12;
#pragma unroll
    for (int i = 0; i < 4; ++i) {
      const float a0 = Pm[0] * px[i] + Pm[1] * py[i] + Pm[2]  * pz[i] + Pm[3];
      const float a1 = Pm[4] * px[i] + Pm[5] * py[i] + Pm[6]  * pz[i] + Pm[7];
      const float a2 = Pm[8] * px[i] + Pm[9] * py[i] + Pm[10] * pz[i] + Pm[11];
      const float inv = 1.0f / (a2 + 1e-10f);
      const float dx = a0 * inv - tx[v][i];
      const float dy = a1 * inv - ty[v][i];
      sum_dist += dx * dx + dy * dy;
    }
  }

  // ============== wave shuffle reduction (f32, deterministic) ==============
#pragma unroll
  for (int o = 32; o > 0; o >>= 1) {
    sum_diff2 += __shfl_down(sum_diff2, o);
    sum_dist  += __shfl_down(sum_dist,  o);
    sum_acc2  += __shfl_down(sum_acc2,  o);
    cntf      += __shfl_down(cntf,      o);
#pragma unroll
    for (int k = 0; k < 3; ++k) {
      gmin[k] = fminf(gmin[k], __shfl_down(gmin[k], o));
      gmax[k] = fmaxf(gmax[k], __shfl_down(gmax[k], o));
      pmin[k] = fminf(pmin[k], __shfl_down(pmin[k], o));
      pmax[k] = fmaxf(pmax[k], __shfl_down(pmax[k], o));
    }
  }

  __shared__ Partial sw[NTHR / 64];
  const int lane = threadIdx.x & 63;
  const int wave = threadIdx.x >> 6;
  if (lane == 0) {
    Partial p;
    p.sum_diff2 = sum_diff2; p.sum_dist = sum_dist;
    p.sum_acc2  = sum_acc2;  p.cnt      = cntf;
#pragma unroll
    for (int k = 0; k < 3; ++k) {
      p.gmin[k] = gmin[k]; p.gmax[k] = gmax[k];
      p.pmin[k] = pmin[k]; p.pmax[k] = pmax[k];
    }
    sw[wave] = p;
  }
  __syncthreads();
  if (threadIdx.x == 0) {
    Partial p = sw[0];
#pragma unroll
    for (int w = 1; w < NTHR / 64; ++w) {
      p.sum_diff2 += sw[w].sum_diff2; p.sum_dist += sw[w].sum_dist;
      p.sum_acc2  += sw[w].sum_acc2;  p.cnt      += sw[w].cnt;
#pragma unroll
      for (int k = 0; k < 3; ++k) {
        p.gmin[k] = fminf(p.gmin[k], sw[w].gmin[k]);
        p.gmax[k] = fmaxf(p.gmax[k], sw[w].gmax[k]);
        p.pmin[k] = fminf(p.pmin[k], sw[w].pmin[k]);
        p.pmax[k] = fmaxf(p.pmax[k], sw[w].pmax[k]);
      }
    }
    partials[blockIdx.x] = p;
  }
}

__global__ __launch_bounds__(NTHR) void loss_final(
    const Partial* __restrict__ partials, float* __restrict__ out)
{
  float sum_diff2 = 0.0f, sum_dist = 0.0f, sum_acc2 = 0.0f, cnt = 0.0f;
  float gmin[3] = { INFINITY,  INFINITY,  INFINITY};
  float gmax[3] = {-INFINITY, -INFINITY, -INFINITY};
  float pmin[3] = { INFINITY,  INFINITY,  INFINITY};
  float pmax[3] = {-INFINITY, -INFINITY, -INFINITY};

  const int tid = threadIdx.x;
  for (int i = tid; i < NBLK; i += NTHR) {   // fixed order -> deterministic
    const Partial p = partials[i];
    sum_diff2 += p.sum_diff2; sum_dist += p.sum_dist;
    sum_acc2  += p.sum_acc2;  cnt      += p.cnt;
#pragma unroll
    for (int k = 0; k < 3; ++k) {
      gmin[k] = fminf(gmin[k], p.gmin[k]); gmax[k] = fmaxf(gmax[k], p.gmax[k]);
      pmin[k] = fminf(pmin[k], p.pmin[k]); pmax[k] = fmaxf(pmax[k], p.pmax[k]);
    }
  }

#pragma unroll
  for (int o = 32; o > 0; o >>= 1) {
    sum_diff2 += __shfl_down(sum_diff2, o);
    sum_dist  += __shfl_down(sum_dist,  o);
    sum_acc2  += __shfl_down(sum_acc2,  o);
    cnt       += __shfl_down(cnt,       o);
#pragma unroll
    for (int k = 0; k < 3; ++k) {
      gmin[k] = fminf(gmin[k], __shfl_down(gmin[k], o));
      gmax[k] = fmaxf(gmax[k], __shfl_down(gmax[k], o));
      pmin[k] = fminf(pmin[k], __shfl_down(pmin[k], o));
      pmax[k] = fmaxf(pmax[k], __shfl_down(pmax[k], o));
    }
  }

  __shared__ Partial sw[NTHR / 64];
  const int lane = tid & 63;
  const int wave = tid >> 6;
  if (lane == 0) {
    Partial p;
    p.sum_diff2 = sum_diff2; p.sum_dist = sum_dist;
    p.sum_acc2  = sum_acc2;  p.cnt      = cnt;
#pragma unroll
    for (int k = 0; k < 3; ++k) {
      p.gmin[k] = gmin[k]; p.gmax[k] = gmax[k];
      p.pmin[k] = pmin[k]; p.pmax[k] = pmax[k];
    }
    sw[wave] = p;
  }
  __syncthreads();

  if (tid == 0) {
    Partial p = sw[0];
#pragma unroll
    for (int w = 1; w < NTHR / 64; ++w) {
      p.sum_diff2 += sw[w].sum_diff2; p.sum_dist += sw[w].sum_dist;
      p.sum_acc2  += sw[w].sum_acc2;  p.cnt      += sw[w].cnt;
#pragma unroll
      for (int k = 0; k < 3; ++k) {
        p.gmin[k] = fminf(p.gmin[k], sw[w].gmin[k]);
        p.gmax[k] = fmaxf(p.gmax[k], sw[w].gmax[k]);
        p.pmin[k] = fminf(p.pmin[k], sw[w].pmin[k]);
        p.pmax[k] = fmaxf(p.pmax[k], sw[w].pmax[k]);
      }
    }

    double sr = -INFINITY;
#pragma unroll
    for (int k = 0; k < 3; ++k) sr = fmax(sr, (double)p.gmax[k] - (double)p.gmin[k]);
    sr += 1e-6;
    const double recon = (double)p.sum_diff2 / fmax((double)p.cnt * 3.0, 1.0) / (sr * sr);

    const double ident = (double)p.sum_dist / 224.0 / ((double)V_ * B_ * F_ * N_ * 2.0);

    double st = -INFINITY;
#pragma unroll
    for (int k = 0; k < 3; ++k) st = fmax(st, (double)p.pmax[k] - (double)p.pmin[k]);
    st += 1e-6;
    const double tloss = (double)p.sum_acc2 / ((double)B_ * (F_ - 2) * N_);
    const double temp = tloss / (st * st);

    const double total = recon + ident + 0.5 * temp;
    out[0] = (float)total;
    out[1] = (float)recon;
    out[2] = (float)ident;
    out[3] = (float)temp;
  }
}

extern "C" void kernel_launch(void* const* d_in, const int* in_sizes, int n_in,
                              void* d_out, int out_size, void* d_ws, size_t ws_size,
                              hipStream_t stream) {
  const float* pred   = (const float*)d_in[0];
  const float* gt     = (const float*)d_in[1];
  const int*   vis    = (const int*)d_in[2];
  const float* P      = (const float*)d_in[3];
  const float* tracks = (const float*)d_in[4];
  float* out = (float*)d_out;
  Partial* partials = (Partial*)d_ws;

  loss_main<<<NBLK, NTHR, 0, stream>>>(pred, gt, vis, P, tracks, partials);
  loss_final<<<1, NTHR, 0, stream>>>(partials, out);
}